// Round 15
// baseline (371.930 us; speedup 1.0000x reference)
//
#include <hip/hip_runtime.h>
#include <hip/hip_fp16.h>
#include <math.h>

#define EPSF 1e-15f
#define MAX_ATANH (1.0f - 1e-5f)
#define ATT 16

#define LOG_NPB 11                 // nodes per bucket = 2048
#define NPB (1 << LOG_NPB)
#define MAXB 1024                  // max buckets (V <= 2^21)
#define NBLK 512                   // hist/scatter grid (proven-fast config)

// score table: s(vx, vy) on [-6.25, 6.25]^2, 512x512, bilinear
#define TDIM 512
#define TSPAN 12.5f
#define TSTEP (TSPAN / (float)(TDIM - 1))
#define TSCALE ((float)(TDIM - 1) / TSPAN)
#define TOFF (6.25f * TSCALE)

// rescue threshold: above this |sub| norm, atanh amplification of fp16
// gather error is too large -> refetch exact f32 (rare tail, ~2-4%)
#define NRESCUE 0.97f

// ---- fast branch-free transcendentals --------------------------------------
__device__ __forceinline__ float fast_atanh(float z) {
    return 0.5f * __logf(__fdividef(1.0f + z, 1.0f - z));
}
__device__ __forceinline__ float fast_tanh(float z) {
    return 1.0f - __fdividef(2.0f, __expf(2.0f * z) + 1.0f);
}
__device__ __forceinline__ float gelu_exact(float u) {
    return 0.5f * u * (1.0f + erff(u * 0.70710678118654752f));
}

// ---------------- K0a: build fp16 mirror of x (8MB) ------------------------
__global__ void __launch_bounds__(256) x2h_kernel(const float4* __restrict__ x4,
                                                  __half2* __restrict__ xh, int Vhalf) {
    const int i = blockIdx.x * 256 + threadIdx.x;
    if (i >= Vhalf) return;
    const float4 v = x4[i];
    xh[2 * i]     = __floats2half2_rn(v.x, v.y);
    xh[2 * i + 1] = __floats2half2_rn(v.z, v.w);
}

// ---------------- K0b: build score table (exact erf; ~µs) ------------------
__global__ void __launch_bounds__(256) build_table_kernel(
        const float* __restrict__ W1, const float* __restrict__ b1,
        const float* __restrict__ W2, float2* __restrict__ tab) {
    const int idx = blockIdx.x * 256 + threadIdx.x;
    if (idx >= TDIM * TDIM) return;
    const int iy = idx >> 9;
    const int ix = idx & (TDIM - 1);
    const float vy  = fmaf((float)iy, TSTEP, -6.25f);
    const float vx0 = fmaf((float)ix, TSTEP, -6.25f);
    const float vx1 = fmaf((float)min(ix + 1, TDIM - 1), TSTEP, -6.25f);
    float s0 = 0.0f, s1 = 0.0f;
    #pragma unroll
    for (int k = 0; k < ATT; ++k) {
        const float w1x = W1[k], w1y = W1[ATT + k], bb = b1[k], w2 = W2[k];
        s0 = fmaf(gelu_exact(fmaf(vx0, w1x, fmaf(vy, w1y, bb))), w2, s0);
        s1 = fmaf(gelu_exact(fmaf(vx1, w1x, fmaf(vy, w1y, bb))), w2, s1);
    }
    tab[idx] = make_float2(s0, s1);
}

// ---------------- K1: per-block bucket histogram ---------------------------
__global__ void __launch_bounds__(256) hist_kernel(const int* __restrict__ row,
                                                   int E, int B,
                                                   unsigned* __restrict__ counts /*[B][NBLK]*/) {
    __shared__ unsigned h[MAXB];
    for (int i = threadIdx.x; i < B; i += 256) h[i] = 0u;
    __syncthreads();
    const int T = gridDim.x * 256;
    const int nv = E >> 2;
    const int4* row4 = (const int4*)row;
    for (int i = blockIdx.x * 256 + threadIdx.x; i < nv; i += T) {
        const int4 r = row4[i];
        atomicAdd(&h[((unsigned)r.x) >> LOG_NPB], 1u);
        atomicAdd(&h[((unsigned)r.y) >> LOG_NPB], 1u);
        atomicAdd(&h[((unsigned)r.z) >> LOG_NPB], 1u);
        atomicAdd(&h[((unsigned)r.w) >> LOG_NPB], 1u);
    }
    for (int e = (nv << 2) + blockIdx.x * 256 + threadIdx.x; e < E; e += T)
        atomicAdd(&h[((unsigned)row[e]) >> LOG_NPB], 1u);
    __syncthreads();
    for (int i = threadIdx.x; i < B; i += 256)
        counts[(size_t)i * gridDim.x + blockIdx.x] = h[i];
}

// ---------------- K2a: exclusive scan of each bucket's NBLK counts ---------
// NBLK = 512, 256 threads, exactly 2 elems/thread.
__global__ void __launch_bounds__(256) scan_blocks_kernel(const unsigned* __restrict__ counts,
                                                          unsigned* __restrict__ within,
                                                          unsigned* __restrict__ totals) {
    const int b = blockIdx.x;
    const unsigned* src = counts + (size_t)b * NBLK;
    unsigned* dst = within + (size_t)b * NBLK;
    __shared__ unsigned s[256];
    unsigned v0, v1;
    {
        const uint2 v = ((const uint2*)src)[threadIdx.x];
        v0 = v.x; v1 = v.y;
    }
    s[threadIdx.x] = v0 + v1;
    __syncthreads();
    for (int off = 1; off < 256; off <<= 1) {
        unsigned t = (threadIdx.x >= off) ? s[threadIdx.x - off] : 0u;
        __syncthreads();
        s[threadIdx.x] += t;
        __syncthreads();
    }
    unsigned base = (threadIdx.x > 0) ? s[threadIdx.x - 1] : 0u;
    uint2 o;
    o.x = base; o.y = base + v0;
    ((uint2*)dst)[threadIdx.x] = o;
    if (threadIdx.x == 255) totals[b] = s[255];
}

// ---------------- K2b: exclusive scan of bucket totals -> base[B+1] --------
__global__ void __launch_bounds__(256) scan_totals_kernel(const unsigned* __restrict__ totals,
                                                          unsigned* __restrict__ base, int B) {
    __shared__ unsigned s[256];
    unsigned vals[8];
    const int i0 = threadIdx.x * 8;
    unsigned sum = 0u;
    #pragma unroll
    for (int k = 0; k < 8; ++k) {
        vals[k] = (i0 + k < B) ? totals[i0 + k] : 0u;
        sum += vals[k];
    }
    s[threadIdx.x] = sum;
    __syncthreads();
    for (int off = 1; off < 256; off <<= 1) {
        unsigned t = (threadIdx.x >= off) ? s[threadIdx.x - off] : 0u;
        __syncthreads();
        s[threadIdx.x] += t;
        __syncthreads();
    }
    unsigned b0 = (threadIdx.x > 0) ? s[threadIdx.x - 1] : 0u;
    #pragma unroll
    for (int k = 0; k < 8; ++k) {
        if (i0 + k < B) base[i0 + k] = b0;
        b0 += vals[k];
    }
    if (threadIdx.x == 255) base[B] = s[255];
}

// ---------------- K3: scatter edges + embed fp16 xj into payload -----------
// payload elem (uint2): .x = (lrow:11 << 21) | col:21 ; .y = half2(xj) bits
__global__ void __launch_bounds__(256) scatter_kernel(const int* __restrict__ row,
                                                      const int* __restrict__ col,
                                                      const unsigned* __restrict__ xhbits,
                                                      int E, int B,
                                                      const unsigned* __restrict__ base,
                                                      const unsigned* __restrict__ within,
                                                      uint2* __restrict__ payload) {
    __shared__ unsigned cur[MAXB];
    const int nblk = gridDim.x;
    for (int i = threadIdx.x; i < B; i += 256)
        cur[i] = base[i] + within[(size_t)i * nblk + blockIdx.x];
    __syncthreads();
    const int T = nblk * 256;
    const int nv = E >> 2;
    const int4* row4 = (const int4*)row;
    const int4* col4 = (const int4*)col;
    for (int i = blockIdx.x * 256 + threadIdx.x; i < nv; i += T) {
        const int4 r = row4[i];
        const int4 c = col4[i];
        // issue 4 independent xj gathers up front (MLP in flight)
        const unsigned j0 = xhbits[(unsigned)c.x];
        const unsigned j1 = xhbits[(unsigned)c.y];
        const unsigned j2 = xhbits[(unsigned)c.z];
        const unsigned j3 = xhbits[(unsigned)c.w];
        {
            const unsigned rr = (unsigned)r.x;
            const unsigned pos = atomicAdd(&cur[rr >> LOG_NPB], 1u);
            payload[pos] = make_uint2(((rr & (NPB - 1)) << 21) | (unsigned)c.x, j0);
        }
        {
            const unsigned rr = (unsigned)r.y;
            const unsigned pos = atomicAdd(&cur[rr >> LOG_NPB], 1u);
            payload[pos] = make_uint2(((rr & (NPB - 1)) << 21) | (unsigned)c.y, j1);
        }
        {
            const unsigned rr = (unsigned)r.z;
            const unsigned pos = atomicAdd(&cur[rr >> LOG_NPB], 1u);
            payload[pos] = make_uint2(((rr & (NPB - 1)) << 21) | (unsigned)c.z, j2);
        }
        {
            const unsigned rr = (unsigned)r.w;
            const unsigned pos = atomicAdd(&cur[rr >> LOG_NPB], 1u);
            payload[pos] = make_uint2(((rr & (NPB - 1)) << 21) | (unsigned)c.w, j3);
        }
    }
    for (int e = (nv << 2) + blockIdx.x * 256 + threadIdx.x; e < E; e += T) {
        const unsigned rr = (unsigned)row[e];
        const unsigned cc = (unsigned)col[e];
        const unsigned jb = xhbits[cc];
        const unsigned pos = atomicAdd(&cur[rr >> LOG_NPB], 1u);
        payload[pos] = make_uint2(((rr & (NPB - 1)) << 21) | cc, jb);
    }
}

// ---------------- K4: per-bucket LDS accumulate + node epilogue ------------
// Streams 8B payload (coalesced); NO random gather except rare f32 rescue.
__device__ __forceinline__ void sub_norm(float2 xi, float2 xj,
                                         float& subx, float& suby, float& n) {
    const float ax = -xi.x, ay = -xi.y;
    const float bx = xj.x,  by = xj.y;
    const float a2 = ax * ax + ay * ay;
    const float b2 = bx * bx + by * by;
    const float ab = ax * bx + ay * by;
    const float ca = 1.0f + 2.0f * ab + b2;
    const float cb = 1.0f - a2;
    const float dn = fmaxf(1.0f + 2.0f * ab + a2 * b2, EPSF);
    const float rdn = __fdividef(1.0f, dn);
    subx = (ca * ax + cb * bx) * rdn;
    suby = (ca * ay + cb * by) * rdn;
    n = fmaxf(sqrtf(subx * subx + suby * suby), EPSF);
}

__device__ __forceinline__ void edge_single(uint2 pw, int nodeBase,
        const float2* __restrict__ x, const float2* __restrict__ tab,
        float* sden, float* smx, float* smy) {
    const unsigned p = pw.x;
    const unsigned lrow = p >> 21;
    const unsigned c = p & 0x1FFFFFu;
    const __half2 hj = *reinterpret_cast<const __half2*>(&pw.y);
    float2 xj = __half22float2(hj);              // embedded fp16 xj
    const float2 xi = x[nodeBase + (int)lrow];   // 16KB window, L2-hot, exact

    float subx, suby, n;
    sub_norm(xi, xj, subx, suby, n);
    if (n > NRESCUE) {                           // rare: atanh amplification
        xj = x[c];                               // exact f32 refetch
        sub_norm(xi, xj, subx, suby, n);
    }

    const float M = fmaxf(1.0f - (xi.x * xi.x + xi.y * xi.y), EPSF);
    const float scl = M * fast_atanh(fminf(n, MAX_ATANH)) * __fdividef(1.0f, n);
    const float vx = scl * subx;
    const float vy = scl * suby;

    float tx = fmaf(vx, TSCALE, TOFF);
    float ty = fmaf(vy, TSCALE, TOFF);
    tx = fminf(fmaxf(tx, 0.0f), 510.999f);
    ty = fminf(fmaxf(ty, 0.0f), 510.999f);
    const int ix = (int)tx;
    const int iy = (int)ty;
    const float fx = tx - (float)ix;
    const float fy = ty - (float)iy;
    const int baseIdx = (iy << 9) + ix;
    const float2 r0 = tab[baseIdx];
    const float2 r1 = tab[baseIdx + TDIM];
    const float s0 = fmaf(fx, r0.y - r0.x, r0.x);
    const float s1 = fmaf(fx, r1.y - r1.x, r1.x);
    const float s  = fmaf(fy, s1 - s0, s0);

    const float ee = __expf(s);
    atomicAdd(&sden[lrow], ee);
    atomicAdd(&smx[lrow], ee * vx);
    atomicAdd(&smy[lrow], ee * vy);
}

__global__ void __launch_bounds__(512, 8) bucket_reduce_kernel(
        const float2* __restrict__ x,
        const float2* __restrict__ tab,
        const unsigned* __restrict__ base,
        const uint2* __restrict__ payload,
        const int* __restrict__ depth,
        const float* __restrict__ depth_scale,
        const float* __restrict__ depth_theta,
        const float* __restrict__ eta_p,
        float2* __restrict__ out, int V) {
    __shared__ float  sden[NPB];
    __shared__ float  smx[NPB];
    __shared__ float  smy[NPB];
    const int b = blockIdx.x;
    const int nodeBase = b << LOG_NPB;
    for (int i = threadIdx.x; i < NPB; i += 512) {
        sden[i] = 0.f; smx[i] = 0.f; smy[i] = 0.f;
    }
    __syncthreads();

    const unsigned e0 = base[b], e1 = base[b + 1];
    for (unsigned e = e0 + threadIdx.x; e < e1; e += 512)
        edge_single(payload[e], nodeBase, x, tab, sden, smx, smy);
    __syncthreads();

    // node epilogue: normalize, depth mixer, exp-map (all exact f32)
    const float eta = eta_p[0];
    for (int i = threadIdx.x; i < NPB; i += 512) {
        const int v = nodeBase + i;
        if (v >= V) break;
        const float rdv = __fdividef(1.0f, fmaxf(sden[i], EPSF));
        const float mx = smx[i] * rdv;
        const float my = smy[i] * rdv;

        const int d = min(depth[v], 511);
        const float k   = depth_scale[d];
        const float ang = depth_theta[d];
        const float cs = __cosf(ang), sn = __sinf(ang);
        const float m0 = eta * (k * (cs * mx - sn * my));
        const float m1 = eta * (k * (sn * mx + cs * my));

        const float2 xi = x[v];                  // coalesced, exact

        const float n = fmaxf(sqrtf(m0 * m0 + m1 * m1), EPSF);
        const float M = fmaxf(1.0f - (xi.x * xi.x + xi.y * xi.y), EPSF);
        const float t = fast_tanh(__fdividef(n, M));
        const float tn = t * __fdividef(1.0f, n);
        const float bx = tn * m0;
        const float by = tn * m1;

        const float a2 = xi.x * xi.x + xi.y * xi.y;
        const float b2 = bx * bx + by * by;
        const float ab = xi.x * bx + xi.y * by;
        const float ca = 1.0f + 2.0f * ab + b2;
        const float cb = 1.0f - a2;
        const float dn = fmaxf(1.0f + 2.0f * ab + a2 * b2, EPSF);
        const float rdn = __fdividef(1.0f, dn);

        out[v] = make_float2((ca * xi.x + cb * bx) * rdn,
                             (ca * xi.y + cb * by) * rdn);
    }
}

extern "C" void kernel_launch(void* const* d_in, const int* in_sizes, int n_in,
                              void* d_out, int out_size, void* d_ws, size_t ws_size,
                              hipStream_t stream) {
    const float2* x          = (const float2*)d_in[0];
    const float*  W1         = (const float*)d_in[1];
    const float*  b1         = (const float*)d_in[2];
    const float*  W2         = (const float*)d_in[3];
    const float*  eta        = (const float*)d_in[4];
    const float*  dscale     = (const float*)d_in[5];
    const float*  dtheta     = (const float*)d_in[6];
    const int*    edge_index = (const int*)d_in[7];
    const int*    depth      = (const int*)d_in[8];

    const int V = in_sizes[0] / 2;
    const int E = in_sizes[7] / 2;
    const int B = (V + NPB - 1) >> LOG_NPB;       // 1024 buckets

    const int* row = edge_index;
    const int* col = edge_index + E;

    // workspace layout (u32 words):
    //   payload[2*E] (uint2, 64MB) | counts[B*NBLK] | within[B*NBLK]
    //   | totals[B] | base[B+1] | xh[V] (half2 = 1 word/node, 8MB)
    // score table (2MB float2) reuses `within` (dead after scatter).
    unsigned* payw    = (unsigned*)d_ws;
    unsigned* counts  = payw + 2 * (size_t)E;
    unsigned* within  = counts + (size_t)B * NBLK;
    unsigned* totals  = within + (size_t)B * NBLK;
    unsigned* base    = totals + B;
    unsigned* xhbits  = base + B + 1;
    uint2*    payload = (uint2*)payw;
    __half2*  xh      = (__half2*)xhbits;
    float2*   tab     = (float2*)within;

    hist_kernel<<<NBLK, 256, 0, stream>>>(row, E, B, counts);
    scan_blocks_kernel<<<B, 256, 0, stream>>>(counts, within, totals);
    scan_totals_kernel<<<1, 256, 0, stream>>>(totals, base, B);
    x2h_kernel<<<(V / 2 + 255) / 256, 256, 0, stream>>>((const float4*)x, xh, V / 2);
    scatter_kernel<<<NBLK, 256, 0, stream>>>(row, col, xhbits, E, B, base, within, payload);
    build_table_kernel<<<(TDIM * TDIM) / 256, 256, 0, stream>>>(W1, b1, W2, tab);
    bucket_reduce_kernel<<<B, 512, 0, stream>>>(x, tab, base, payload,
                                                depth, dscale, dtheta, eta,
                                                (float2*)d_out, V);
}

// Round 16
// 295.001 us; speedup vs baseline: 1.2608x; 1.2608x over previous
//
#include <hip/hip_runtime.h>
#include <math.h>

#define EPSF 1e-15f
#define MAX_ATANH (1.0f - 1e-5f)
#define ATT 16

#define LOG_NPB 10                 // nodes per bucket = 1024 (fast-reduce shape)
#define NPB (1 << LOG_NPB)
#define MAXB 2048                  // max buckets (V <= 2^21)
#define NBLK 512                   // blocks in hist/scatter kernels
#define PAD 16                     // 64B inter-bucket gap: decorrelates write
                                   // frontiers across L2 sets (anti-aliasing)

// score table: s(vx, vy) on [-6.25, 6.25]^2, 512x512, bilinear
#define TDIM 512
#define TSPAN 12.5f
#define TSTEP (TSPAN / (float)(TDIM - 1))
#define TSCALE ((float)(TDIM - 1) / TSPAN)
#define TOFF (6.25f * TSCALE)

// ---- fast branch-free transcendentals --------------------------------------
__device__ __forceinline__ float fast_atanh(float z) {
    return 0.5f * __logf(__fdividef(1.0f + z, 1.0f - z));
}
__device__ __forceinline__ float fast_tanh(float z) {
    return 1.0f - __fdividef(2.0f, __expf(2.0f * z) + 1.0f);
}
__device__ __forceinline__ float gelu_exact(float u) {
    return 0.5f * u * (1.0f + erff(u * 0.70710678118654752f));
}

// ---------------- K0: build score table (exact erf; ~µs) -------------------
__global__ void __launch_bounds__(256) build_table_kernel(
        const float* __restrict__ W1, const float* __restrict__ b1,
        const float* __restrict__ W2, float2* __restrict__ tab) {
    const int idx = blockIdx.x * 256 + threadIdx.x;
    if (idx >= TDIM * TDIM) return;
    const int iy = idx >> 9;
    const int ix = idx & (TDIM - 1);
    const float vy  = fmaf((float)iy, TSTEP, -6.25f);
    const float vx0 = fmaf((float)ix, TSTEP, -6.25f);
    const float vx1 = fmaf((float)min(ix + 1, TDIM - 1), TSTEP, -6.25f);
    float s0 = 0.0f, s1 = 0.0f;
    #pragma unroll
    for (int k = 0; k < ATT; ++k) {
        const float w1x = W1[k], w1y = W1[ATT + k], bb = b1[k], w2 = W2[k];
        s0 = fmaf(gelu_exact(fmaf(vx0, w1x, fmaf(vy, w1y, bb))), w2, s0);
        s1 = fmaf(gelu_exact(fmaf(vx1, w1x, fmaf(vy, w1y, bb))), w2, s1);
    }
    tab[idx] = make_float2(s0, s1);
}

// ---------------- K1: per-block bucket histogram ---------------------------
__global__ void __launch_bounds__(256) hist_kernel(const int* __restrict__ row,
                                                   int E, int B,
                                                   unsigned* __restrict__ counts /*[B][NBLK]*/) {
    __shared__ unsigned h[MAXB];
    for (int i = threadIdx.x; i < B; i += 256) h[i] = 0u;
    __syncthreads();
    const int T = gridDim.x * 256;
    const int nv = E >> 2;
    const int4* row4 = (const int4*)row;
    for (int i = blockIdx.x * 256 + threadIdx.x; i < nv; i += T) {
        const int4 r = row4[i];
        atomicAdd(&h[((unsigned)r.x) >> LOG_NPB], 1u);
        atomicAdd(&h[((unsigned)r.y) >> LOG_NPB], 1u);
        atomicAdd(&h[((unsigned)r.z) >> LOG_NPB], 1u);
        atomicAdd(&h[((unsigned)r.w) >> LOG_NPB], 1u);
    }
    for (int e = (nv << 2) + blockIdx.x * 256 + threadIdx.x; e < E; e += T)
        atomicAdd(&h[((unsigned)row[e]) >> LOG_NPB], 1u);
    __syncthreads();
    for (int i = threadIdx.x; i < B; i += 256)
        counts[(size_t)i * gridDim.x + blockIdx.x] = h[i];
}

// ---------------- K2a: exclusive scan of each bucket's NBLK counts ---------
// NBLK = 512, 256 threads, exactly 2 elems/thread.
__global__ void __launch_bounds__(256) scan_blocks_kernel(const unsigned* __restrict__ counts,
                                                          unsigned* __restrict__ within,
                                                          unsigned* __restrict__ totals) {
    const int b = blockIdx.x;
    const unsigned* src = counts + (size_t)b * NBLK;
    unsigned* dst = within + (size_t)b * NBLK;
    __shared__ unsigned s[256];
    unsigned v0, v1;
    {
        const uint2 v = ((const uint2*)src)[threadIdx.x];
        v0 = v.x; v1 = v.y;
    }
    s[threadIdx.x] = v0 + v1;
    __syncthreads();
    for (int off = 1; off < 256; off <<= 1) {
        unsigned t = (threadIdx.x >= off) ? s[threadIdx.x - off] : 0u;
        __syncthreads();
        s[threadIdx.x] += t;
        __syncthreads();
    }
    unsigned base = (threadIdx.x > 0) ? s[threadIdx.x - 1] : 0u;
    uint2 o;
    o.x = base; o.y = base + v0;
    ((uint2*)dst)[threadIdx.x] = o;
    if (threadIdx.x == 255) totals[b] = s[255];
}

// ---------------- K2b: scan of totals -> STAGGERED base[B+1] ---------------
// base[b] = prefix_sum(totals[0..b)) + b*PAD  (64B gap per bucket region)
__global__ void __launch_bounds__(256) scan_totals_kernel(const unsigned* __restrict__ totals,
                                                          unsigned* __restrict__ base, int B) {
    __shared__ unsigned s[256];
    unsigned vals[8];
    const int i0 = threadIdx.x * 8;
    unsigned sum = 0u;
    #pragma unroll
    for (int k = 0; k < 8; ++k) {
        vals[k] = (i0 + k < B) ? totals[i0 + k] : 0u;
        sum += vals[k];
    }
    s[threadIdx.x] = sum;
    __syncthreads();
    for (int off = 1; off < 256; off <<= 1) {
        unsigned t = (threadIdx.x >= off) ? s[threadIdx.x - off] : 0u;
        __syncthreads();
        s[threadIdx.x] += t;
        __syncthreads();
    }
    unsigned b0 = (threadIdx.x > 0) ? s[threadIdx.x - 1] : 0u;
    #pragma unroll
    for (int k = 0; k < 8; ++k) {
        if (i0 + k < B) base[i0 + k] = b0 + (unsigned)(i0 + k) * PAD;
        b0 += vals[k];
    }
    if (threadIdx.x == 255) base[B] = s[255] + (unsigned)B * PAD;
}

// ---------------- K3: scatter edges into bucket-sorted payload -------------
// payload word: (lrow:10 << 21) | col:21   (V <= 2^21)
__global__ void __launch_bounds__(256) scatter_kernel(const int* __restrict__ row,
                                                      const int* __restrict__ col,
                                                      int E, int B,
                                                      const unsigned* __restrict__ base,
                                                      const unsigned* __restrict__ within,
                                                      unsigned* __restrict__ payload) {
    __shared__ unsigned cur[MAXB];
    const int nblk = gridDim.x;
    for (int i = threadIdx.x; i < B; i += 256)
        cur[i] = base[i] + within[(size_t)i * nblk + blockIdx.x];
    __syncthreads();
    const int T = nblk * 256;
    const int nv = E >> 2;
    const int4* row4 = (const int4*)row;
    const int4* col4 = (const int4*)col;
    for (int i = blockIdx.x * 256 + threadIdx.x; i < nv; i += T) {
        const int4 r = row4[i];
        const int4 c = col4[i];
        {
            const unsigned rr = (unsigned)r.x;
            const unsigned pos = atomicAdd(&cur[rr >> LOG_NPB], 1u);
            payload[pos] = ((rr & (NPB - 1)) << 21) | (unsigned)c.x;
        }
        {
            const unsigned rr = (unsigned)r.y;
            const unsigned pos = atomicAdd(&cur[rr >> LOG_NPB], 1u);
            payload[pos] = ((rr & (NPB - 1)) << 21) | (unsigned)c.y;
        }
        {
            const unsigned rr = (unsigned)r.z;
            const unsigned pos = atomicAdd(&cur[rr >> LOG_NPB], 1u);
            payload[pos] = ((rr & (NPB - 1)) << 21) | (unsigned)c.z;
        }
        {
            const unsigned rr = (unsigned)r.w;
            const unsigned pos = atomicAdd(&cur[rr >> LOG_NPB], 1u);
            payload[pos] = ((rr & (NPB - 1)) << 21) | (unsigned)c.w;
        }
    }
    for (int e = (nv << 2) + blockIdx.x * 256 + threadIdx.x; e < E; e += T) {
        const unsigned rr = (unsigned)row[e];
        const unsigned pos = atomicAdd(&cur[rr >> LOG_NPB], 1u);
        payload[pos] = ((rr & (NPB - 1)) << 21) | (unsigned)col[e];
    }
}

// ---------------- K4: per-bucket LDS accumulate + node epilogue ------------
// NPB=1024, 512 threads, 20KB LDS (proven-fast reduce shape).
__device__ __forceinline__ void edge_single(unsigned p,
        const float2* __restrict__ x, const float2* __restrict__ tab,
        const float2* sxi, float* sden, float* smx, float* smy) {
    const unsigned lrow = p >> 21;
    const unsigned c = p & 0x1FFFFFu;
    const float2 xj = x[c];                      // random gather, L2/L3
    const float2 xi = sxi[lrow];                 // LDS

    const float ax = -xi.x, ay = -xi.y;
    const float bx = xj.x,  by = xj.y;
    const float a2 = ax * ax + ay * ay;
    const float b2 = bx * bx + by * by;
    const float ab = ax * bx + ay * by;
    const float ca = 1.0f + 2.0f * ab + b2;
    const float cb = 1.0f - a2;
    const float dn = fmaxf(1.0f + 2.0f * ab + a2 * b2, EPSF);
    const float rdn = __fdividef(1.0f, dn);
    const float subx = (ca * ax + cb * bx) * rdn;
    const float suby = (ca * ay + cb * by) * rdn;

    const float n = fmaxf(sqrtf(subx * subx + suby * suby), EPSF);
    const float M = fmaxf(1.0f - (xi.x * xi.x + xi.y * xi.y), EPSF);
    const float scl = M * fast_atanh(fminf(n, MAX_ATANH)) * __fdividef(1.0f, n);
    const float vx = scl * subx;
    const float vy = scl * suby;

    float tx = fmaf(vx, TSCALE, TOFF);
    float ty = fmaf(vy, TSCALE, TOFF);
    tx = fminf(fmaxf(tx, 0.0f), 510.999f);
    ty = fminf(fmaxf(ty, 0.0f), 510.999f);
    const int ix = (int)tx;
    const int iy = (int)ty;
    const float fx = tx - (float)ix;
    const float fy = ty - (float)iy;
    const int baseIdx = (iy << 9) + ix;
    const float2 r0 = tab[baseIdx];
    const float2 r1 = tab[baseIdx + TDIM];
    const float s0 = fmaf(fx, r0.y - r0.x, r0.x);
    const float s1 = fmaf(fx, r1.y - r1.x, r1.x);
    const float s  = fmaf(fy, s1 - s0, s0);

    const float ee = __expf(s);
    atomicAdd(&sden[lrow], ee);
    atomicAdd(&smx[lrow], ee * vx);
    atomicAdd(&smy[lrow], ee * vy);
}

__global__ void __launch_bounds__(512, 8) bucket_reduce_kernel(
        const float2* __restrict__ x,
        const float2* __restrict__ tab,
        const unsigned* __restrict__ base,
        const unsigned* __restrict__ payload,
        const int* __restrict__ depth,
        const float* __restrict__ depth_scale,
        const float* __restrict__ depth_theta,
        const float* __restrict__ eta_p,
        float2* __restrict__ out, int V) {
    __shared__ float  sden[NPB];
    __shared__ float  smx[NPB];
    __shared__ float  smy[NPB];
    __shared__ float2 sxi[NPB];
    const int b = blockIdx.x;
    const int nodeBase = b << LOG_NPB;
    for (int i = threadIdx.x; i < NPB; i += 512) {
        sden[i] = 0.f; smx[i] = 0.f; smy[i] = 0.f;
        sxi[i] = x[nodeBase + i];
    }
    __syncthreads();

    // bucket b's edges: [base[b], base[b+1] - PAD)  (staggered layout)
    const unsigned e0 = base[b], e1 = base[b + 1] - PAD;
    for (unsigned e = e0 + threadIdx.x; e < e1; e += 512)
        edge_single(payload[e], x, tab, sxi, sden, smx, smy);
    __syncthreads();

    // node epilogue: normalize, depth mixer, exp-map
    const float eta = eta_p[0];
    for (int i = threadIdx.x; i < NPB; i += 512) {
        const int v = nodeBase + i;
        if (v >= V) break;
        const float rdv = __fdividef(1.0f, fmaxf(sden[i], EPSF));
        const float mx = smx[i] * rdv;
        const float my = smy[i] * rdv;

        const int d = min(depth[v], 511);
        const float k   = depth_scale[d];
        const float ang = depth_theta[d];
        const float cs = __cosf(ang), sn = __sinf(ang);
        const float m0 = eta * (k * (cs * mx - sn * my));
        const float m1 = eta * (k * (sn * mx + cs * my));

        const float2 xi = sxi[i];

        const float n = fmaxf(sqrtf(m0 * m0 + m1 * m1), EPSF);
        const float M = fmaxf(1.0f - (xi.x * xi.x + xi.y * xi.y), EPSF);
        const float t = fast_tanh(__fdividef(n, M));
        const float tn = t * __fdividef(1.0f, n);
        const float bx = tn * m0;
        const float by = tn * m1;

        const float a2 = xi.x * xi.x + xi.y * xi.y;
        const float b2 = bx * bx + by * by;
        const float ab = xi.x * bx + xi.y * by;
        const float ca = 1.0f + 2.0f * ab + b2;
        const float cb = 1.0f - a2;
        const float dn = fmaxf(1.0f + 2.0f * ab + a2 * b2, EPSF);
        const float rdn = __fdividef(1.0f, dn);

        out[v] = make_float2((ca * xi.x + cb * bx) * rdn,
                             (ca * xi.y + cb * by) * rdn);
    }
}

extern "C" void kernel_launch(void* const* d_in, const int* in_sizes, int n_in,
                              void* d_out, int out_size, void* d_ws, size_t ws_size,
                              hipStream_t stream) {
    const float2* x          = (const float2*)d_in[0];
    const float*  W1         = (const float*)d_in[1];
    const float*  b1         = (const float*)d_in[2];
    const float*  W2         = (const float*)d_in[3];
    const float*  eta        = (const float*)d_in[4];
    const float*  dscale     = (const float*)d_in[5];
    const float*  dtheta     = (const float*)d_in[6];
    const int*    edge_index = (const int*)d_in[7];
    const int*    depth      = (const int*)d_in[8];

    const int V = in_sizes[0] / 2;
    const int E = in_sizes[7] / 2;
    const int B = (V + NPB - 1) >> LOG_NPB;       // 2048 buckets

    const int* row = edge_index;
    const int* col = edge_index + E;

    // workspace layout (u32 words): payload[E + B*PAD] | counts[B*NBLK]
    //   | within[B*NBLK] | totals[B] | base[B+1]
    // score table (2MB float2) reuses `within` (4MB, dead after scatter).
    unsigned* payload = (unsigned*)d_ws;
    unsigned* counts  = payload + (size_t)E + (size_t)B * PAD;
    unsigned* within  = counts + (size_t)B * NBLK;
    unsigned* totals  = within + (size_t)B * NBLK;
    unsigned* base    = totals + B;
    float2*   tab     = (float2*)within;

    hist_kernel<<<NBLK, 256, 0, stream>>>(row, E, B, counts);
    scan_blocks_kernel<<<B, 256, 0, stream>>>(counts, within, totals);
    scan_totals_kernel<<<1, 256, 0, stream>>>(totals, base, B);
    scatter_kernel<<<NBLK, 256, 0, stream>>>(row, col, E, B, base, within, payload);
    build_table_kernel<<<(TDIM * TDIM) / 256, 256, 0, stream>>>(W1, b1, W2, tab);
    bucket_reduce_kernel<<<B, 512, 0, stream>>>(x, tab, base, payload,
                                                depth, dscale, dtheta, eta,
                                                (float2*)d_out, V);
}

// Round 17
// 284.386 us; speedup vs baseline: 1.3078x; 1.0373x over previous
//
#include <hip/hip_runtime.h>
#include <math.h>

#define EPSF 1e-15f
#define MAX_ATANH (1.0f - 1e-5f)
#define ATT 16

#define LOG_NPR 10                 // reduce: nodes per sub-bucket = 1024
#define NPR (1 << LOG_NPR)
#define LOG_NPM 11                 // scatter: nodes per merged bucket = 2048
#define NPM (1 << LOG_NPM)
#define B2MAX 2048                 // max sub-buckets  (V <= 2^21)
#define BMMAX 1024                 // max merged buckets
#define NBLK 512                   // hist/scatter grid

// score table: s(vx, vy) on [-6.25, 6.25]^2, 512x512, bilinear
#define TDIM 512
#define TSPAN 12.5f
#define TSTEP (TSPAN / (float)(TDIM - 1))
#define TSCALE ((float)(TDIM - 1) / TSPAN)
#define TOFF (6.25f * TSCALE)

// ---- fast branch-free transcendentals --------------------------------------
__device__ __forceinline__ float fast_atanh(float z) {
    return 0.5f * __logf(__fdividef(1.0f + z, 1.0f - z));
}
__device__ __forceinline__ float fast_tanh(float z) {
    return 1.0f - __fdividef(2.0f, __expf(2.0f * z) + 1.0f);
}
__device__ __forceinline__ float gelu_exact(float u) {
    return 0.5f * u * (1.0f + erff(u * 0.70710678118654752f));
}

// ---------------- K0: build score table (exact erf; ~µs) -------------------
__global__ void __launch_bounds__(256) build_table_kernel(
        const float* __restrict__ W1, const float* __restrict__ b1,
        const float* __restrict__ W2, float2* __restrict__ tab) {
    const int idx = blockIdx.x * 256 + threadIdx.x;
    if (idx >= TDIM * TDIM) return;
    const int iy = idx >> 9;
    const int ix = idx & (TDIM - 1);
    const float vy  = fmaf((float)iy, TSTEP, -6.25f);
    const float vx0 = fmaf((float)ix, TSTEP, -6.25f);
    const float vx1 = fmaf((float)min(ix + 1, TDIM - 1), TSTEP, -6.25f);
    float s0 = 0.0f, s1 = 0.0f;
    #pragma unroll
    for (int k = 0; k < ATT; ++k) {
        const float w1x = W1[k], w1y = W1[ATT + k], bb = b1[k], w2 = W2[k];
        s0 = fmaf(gelu_exact(fmaf(vx0, w1x, fmaf(vy, w1y, bb))), w2, s0);
        s1 = fmaf(gelu_exact(fmaf(vx1, w1x, fmaf(vy, w1y, bb))), w2, s1);
    }
    tab[idx] = make_float2(s0, s1);
}

// ---------------- K1: per-block SUB-bucket histogram (2048 bins) -----------
__global__ void __launch_bounds__(256) hist_kernel(const int* __restrict__ row,
                                                   int E, int B2,
                                                   unsigned* __restrict__ counts2 /*[B2][NBLK]*/) {
    __shared__ unsigned h[B2MAX];
    for (int i = threadIdx.x; i < B2; i += 256) h[i] = 0u;
    __syncthreads();
    const int T = gridDim.x * 256;
    const int nv = E >> 2;
    const int4* row4 = (const int4*)row;
    for (int i = blockIdx.x * 256 + threadIdx.x; i < nv; i += T) {
        const int4 r = row4[i];
        atomicAdd(&h[((unsigned)r.x) >> LOG_NPR], 1u);
        atomicAdd(&h[((unsigned)r.y) >> LOG_NPR], 1u);
        atomicAdd(&h[((unsigned)r.z) >> LOG_NPR], 1u);
        atomicAdd(&h[((unsigned)r.w) >> LOG_NPR], 1u);
    }
    for (int e = (nv << 2) + blockIdx.x * 256 + threadIdx.x; e < E; e += T)
        atomicAdd(&h[((unsigned)row[e]) >> LOG_NPR], 1u);
    __syncthreads();
    for (int i = threadIdx.x; i < B2; i += 256)
        counts2[(size_t)i * gridDim.x + blockIdx.x] = h[i];
}

// ---------------- K2a: per-MERGED-bucket scan over blocks ------------------
// Row b (merged) reads sub-rows 2b, 2b+1 of counts2; produces:
//   within[b*NBLK+blk] = exclusive prefix over blk of merged counts
//   totals2[2b], totals2[2b+1] = sub-bucket totals
__global__ void __launch_bounds__(256) scan_blocks_kernel(const unsigned* __restrict__ counts2,
                                                          unsigned* __restrict__ within,
                                                          unsigned* __restrict__ totals2) {
    const int b = blockIdx.x;
    const uint2 r0 = ((const uint2*)(counts2 + (size_t)(2 * b)     * NBLK))[threadIdx.x];
    const uint2 r1 = ((const uint2*)(counts2 + (size_t)(2 * b + 1) * NBLK))[threadIdx.x];
    const unsigned c0 = r0.x + r1.x;   // merged count, blk = 2t
    const unsigned c1 = r0.y + r1.y;   // merged count, blk = 2t+1
    __shared__ unsigned s[256];
    __shared__ unsigned sa[256], sb[256];
    s[threadIdx.x] = c0 + c1;
    sa[threadIdx.x] = r0.x + r0.y;
    sb[threadIdx.x] = r1.x + r1.y;
    __syncthreads();
    for (int off = 1; off < 256; off <<= 1) {
        unsigned t = (threadIdx.x >= off) ? s[threadIdx.x - off] : 0u;
        __syncthreads();
        s[threadIdx.x] += t;
        __syncthreads();
    }
    unsigned base = (threadIdx.x > 0) ? s[threadIdx.x - 1] : 0u;
    uint2 o;
    o.x = base; o.y = base + c0;
    ((uint2*)(within + (size_t)b * NBLK))[threadIdx.x] = o;
    for (int off = 128; off > 0; off >>= 1) {
        if (threadIdx.x < off) { sa[threadIdx.x] += sa[threadIdx.x + off];
                                 sb[threadIdx.x] += sb[threadIdx.x + off]; }
        __syncthreads();
    }
    if (threadIdx.x == 0) { totals2[2 * b] = sa[0]; totals2[2 * b + 1] = sb[0]; }
}

// ---------------- K2b: exclusive scan of totals2 -> base2[B2+1] ------------
__global__ void __launch_bounds__(256) scan_totals_kernel(const unsigned* __restrict__ totals2,
                                                          unsigned* __restrict__ base2, int B2) {
    __shared__ unsigned s[256];
    unsigned vals[8];
    const int i0 = threadIdx.x * 8;
    unsigned sum = 0u;
    #pragma unroll
    for (int k = 0; k < 8; ++k) {
        vals[k] = (i0 + k < B2) ? totals2[i0 + k] : 0u;
        sum += vals[k];
    }
    s[threadIdx.x] = sum;
    __syncthreads();
    for (int off = 1; off < 256; off <<= 1) {
        unsigned t = (threadIdx.x >= off) ? s[threadIdx.x - off] : 0u;
        __syncthreads();
        s[threadIdx.x] += t;
        __syncthreads();
    }
    unsigned b0 = (threadIdx.x > 0) ? s[threadIdx.x - 1] : 0u;
    #pragma unroll
    for (int k = 0; k < 8; ++k) {
        if (i0 + k < B2) base2[i0 + k] = b0;
        b0 += vals[k];
    }
    if (threadIdx.x == 255) base2[B2] = s[255];
}

// ---------------- K3: scatter into 1024 MERGED bucket regions --------------
// payload word: (lrow:11 << 21) | col:21  (lrow within merged bucket)
__global__ void __launch_bounds__(256) scatter_kernel(const int* __restrict__ row,
                                                      const int* __restrict__ col,
                                                      int E, int BM,
                                                      const unsigned* __restrict__ base2,
                                                      const unsigned* __restrict__ within,
                                                      unsigned* __restrict__ payload) {
    __shared__ unsigned cur[BMMAX];
    const int nblk = gridDim.x;
    for (int i = threadIdx.x; i < BM; i += 256)
        cur[i] = base2[2 * i] + within[(size_t)i * nblk + blockIdx.x];
    __syncthreads();
    const int T = nblk * 256;
    const int nv = E >> 2;
    const int4* row4 = (const int4*)row;
    const int4* col4 = (const int4*)col;
    for (int i = blockIdx.x * 256 + threadIdx.x; i < nv; i += T) {
        const int4 r = row4[i];
        const int4 c = col4[i];
        {
            const unsigned rr = (unsigned)r.x;
            const unsigned pos = atomicAdd(&cur[rr >> LOG_NPM], 1u);
            payload[pos] = ((rr & (NPM - 1)) << 21) | (unsigned)c.x;
        }
        {
            const unsigned rr = (unsigned)r.y;
            const unsigned pos = atomicAdd(&cur[rr >> LOG_NPM], 1u);
            payload[pos] = ((rr & (NPM - 1)) << 21) | (unsigned)c.y;
        }
        {
            const unsigned rr = (unsigned)r.z;
            const unsigned pos = atomicAdd(&cur[rr >> LOG_NPM], 1u);
            payload[pos] = ((rr & (NPM - 1)) << 21) | (unsigned)c.z;
        }
        {
            const unsigned rr = (unsigned)r.w;
            const unsigned pos = atomicAdd(&cur[rr >> LOG_NPM], 1u);
            payload[pos] = ((rr & (NPM - 1)) << 21) | (unsigned)c.w;
        }
    }
    for (int e = (nv << 2) + blockIdx.x * 256 + threadIdx.x; e < E; e += T) {
        const unsigned rr = (unsigned)row[e];
        const unsigned pos = atomicAdd(&cur[rr >> LOG_NPM], 1u);
        payload[pos] = ((rr & (NPM - 1)) << 21) | (unsigned)col[e];
    }
}

// ---------------- K3b: split each merged bucket into its two halves --------
// One block per merged bucket; 2 block-exclusive cursors -> good combining.
__global__ void __launch_bounds__(256) split_kernel(const unsigned* __restrict__ base2,
                                                    const unsigned* __restrict__ payload,
                                                    unsigned* __restrict__ payload2) {
    __shared__ unsigned cl, ch;
    const int b = blockIdx.x;
    if (threadIdx.x == 0) { cl = base2[2 * b]; ch = base2[2 * b + 1]; }
    __syncthreads();
    const unsigned e0 = base2[2 * b], e1 = base2[2 * b + 2];
    for (unsigned e = e0 + threadIdx.x; e < e1; e += 256) {
        const unsigned p = payload[e];
        const unsigned lrow11 = p >> 21;
        const unsigned dest = (lrow11 & NPR) ? atomicAdd(&ch, 1u)
                                             : atomicAdd(&cl, 1u);
        payload2[dest] = ((lrow11 & (NPR - 1)) << 21) | (p & 0x1FFFFFu);
    }
}

// ---------------- K4: per-sub-bucket LDS accumulate + node epilogue --------
// NPR=1024, 512 threads, 20KB LDS (proven-fast reduce shape).
__device__ __forceinline__ void edge_single(unsigned p,
        const float2* __restrict__ x, const float2* __restrict__ tab,
        const float2* sxi, float* sden, float* smx, float* smy) {
    const unsigned lrow = p >> 21;
    const unsigned c = p & 0x1FFFFFu;
    const float2 xj = x[c];                      // random gather, L2/L3
    const float2 xi = sxi[lrow];                 // LDS

    const float ax = -xi.x, ay = -xi.y;
    const float bx = xj.x,  by = xj.y;
    const float a2 = ax * ax + ay * ay;
    const float b2 = bx * bx + by * by;
    const float ab = ax * bx + ay * by;
    const float ca = 1.0f + 2.0f * ab + b2;
    const float cb = 1.0f - a2;
    const float dn = fmaxf(1.0f + 2.0f * ab + a2 * b2, EPSF);
    const float rdn = __fdividef(1.0f, dn);
    const float subx = (ca * ax + cb * bx) * rdn;
    const float suby = (ca * ay + cb * by) * rdn;

    const float n = fmaxf(sqrtf(subx * subx + suby * suby), EPSF);
    const float M = fmaxf(1.0f - (xi.x * xi.x + xi.y * xi.y), EPSF);
    const float scl = M * fast_atanh(fminf(n, MAX_ATANH)) * __fdividef(1.0f, n);
    const float vx = scl * subx;
    const float vy = scl * suby;

    float tx = fmaf(vx, TSCALE, TOFF);
    float ty = fmaf(vy, TSCALE, TOFF);
    tx = fminf(fmaxf(tx, 0.0f), 510.999f);
    ty = fminf(fmaxf(ty, 0.0f), 510.999f);
    const int ix = (int)tx;
    const int iy = (int)ty;
    const float fx = tx - (float)ix;
    const float fy = ty - (float)iy;
    const int baseIdx = (iy << 9) + ix;
    const float2 r0 = tab[baseIdx];
    const float2 r1 = tab[baseIdx + TDIM];
    const float s0 = fmaf(fx, r0.y - r0.x, r0.x);
    const float s1 = fmaf(fx, r1.y - r1.x, r1.x);
    const float s  = fmaf(fy, s1 - s0, s0);

    const float ee = __expf(s);
    atomicAdd(&sden[lrow], ee);
    atomicAdd(&smx[lrow], ee * vx);
    atomicAdd(&smy[lrow], ee * vy);
}

__global__ void __launch_bounds__(512, 8) bucket_reduce_kernel(
        const float2* __restrict__ x,
        const float2* __restrict__ tab,
        const unsigned* __restrict__ base2,
        const unsigned* __restrict__ payload2,
        const int* __restrict__ depth,
        const float* __restrict__ depth_scale,
        const float* __restrict__ depth_theta,
        const float* __restrict__ eta_p,
        float2* __restrict__ out, int V) {
    __shared__ float  sden[NPR];
    __shared__ float  smx[NPR];
    __shared__ float  smy[NPR];
    __shared__ float2 sxi[NPR];
    const int b = blockIdx.x;                    // sub-bucket id
    const int nodeBase = b << LOG_NPR;
    for (int i = threadIdx.x; i < NPR; i += 512) {
        sden[i] = 0.f; smx[i] = 0.f; smy[i] = 0.f;
        sxi[i] = x[nodeBase + i];
    }
    __syncthreads();

    const unsigned e0 = base2[b], e1 = base2[b + 1];
    for (unsigned e = e0 + threadIdx.x; e < e1; e += 512)
        edge_single(payload2[e], x, tab, sxi, sden, smx, smy);
    __syncthreads();

    // node epilogue: normalize, depth mixer, exp-map
    const float eta = eta_p[0];
    for (int i = threadIdx.x; i < NPR; i += 512) {
        const int v = nodeBase + i;
        if (v >= V) break;
        const float rdv = __fdividef(1.0f, fmaxf(sden[i], EPSF));
        const float mx = smx[i] * rdv;
        const float my = smy[i] * rdv;

        const int d = min(depth[v], 511);
        const float k   = depth_scale[d];
        const float ang = depth_theta[d];
        const float cs = __cosf(ang), sn = __sinf(ang);
        const float m0 = eta * (k * (cs * mx - sn * my));
        const float m1 = eta * (k * (sn * mx + cs * my));

        const float2 xi = sxi[i];

        const float n = fmaxf(sqrtf(m0 * m0 + m1 * m1), EPSF);
        const float M = fmaxf(1.0f - (xi.x * xi.x + xi.y * xi.y), EPSF);
        const float t = fast_tanh(__fdividef(n, M));
        const float tn = t * __fdividef(1.0f, n);
        const float bx = tn * m0;
        const float by = tn * m1;

        const float a2 = xi.x * xi.x + xi.y * xi.y;
        const float b2 = bx * bx + by * by;
        const float ab = xi.x * bx + xi.y * by;
        const float ca = 1.0f + 2.0f * ab + b2;
        const float cb = 1.0f - a2;
        const float dn = fmaxf(1.0f + 2.0f * ab + a2 * b2, EPSF);
        const float rdn = __fdividef(1.0f, dn);

        out[v] = make_float2((ca * xi.x + cb * bx) * rdn,
                             (ca * xi.y + cb * by) * rdn);
    }
}

extern "C" void kernel_launch(void* const* d_in, const int* in_sizes, int n_in,
                              void* d_out, int out_size, void* d_ws, size_t ws_size,
                              hipStream_t stream) {
    const float2* x          = (const float2*)d_in[0];
    const float*  W1         = (const float*)d_in[1];
    const float*  b1         = (const float*)d_in[2];
    const float*  W2         = (const float*)d_in[3];
    const float*  eta        = (const float*)d_in[4];
    const float*  dscale     = (const float*)d_in[5];
    const float*  dtheta     = (const float*)d_in[6];
    const int*    edge_index = (const int*)d_in[7];
    const int*    depth      = (const int*)d_in[8];

    const int V = in_sizes[0] / 2;
    const int E = in_sizes[7] / 2;
    const int B2 = (V + NPR - 1) >> LOG_NPR;      // 2048 sub-buckets
    const int BM = (V + NPM - 1) >> LOG_NPM;      // 1024 merged buckets

    const int* row = edge_index;
    const int* col = edge_index + E;

    // workspace layout (u32 words):
    //   payload[E] | payload2[E] | counts2[B2*NBLK] | within[BM*NBLK]
    //   | totals2[B2] | base2[B2+1]
    // score table (2MB float2) reuses counts2 (4MB, dead after scan_blocks).
    unsigned* payload  = (unsigned*)d_ws;
    unsigned* payload2 = payload + (size_t)E;
    unsigned* counts2  = payload2 + (size_t)E;
    unsigned* within   = counts2 + (size_t)B2 * NBLK;
    unsigned* totals2  = within + (size_t)BM * NBLK;
    unsigned* base2    = totals2 + B2;
    float2*   tab      = (float2*)counts2;

    hist_kernel<<<NBLK, 256, 0, stream>>>(row, E, B2, counts2);
    scan_blocks_kernel<<<BM, 256, 0, stream>>>(counts2, within, totals2);
    scan_totals_kernel<<<1, 256, 0, stream>>>(totals2, base2, B2);
    scatter_kernel<<<NBLK, 256, 0, stream>>>(row, col, E, BM, base2, within, payload);
    split_kernel<<<BM, 256, 0, stream>>>(base2, payload, payload2);
    build_table_kernel<<<(TDIM * TDIM) / 256, 256, 0, stream>>>(W1, b1, W2, tab);
    bucket_reduce_kernel<<<B2, 512, 0, stream>>>(x, tab, base2, payload2,
                                                 depth, dscale, dtheta, eta,
                                                 (float2*)d_out, V);
}

// Round 18
// 261.916 us; speedup vs baseline: 1.4200x; 1.0858x over previous
//
#include <hip/hip_runtime.h>
#include <math.h>

#define EPSF 1e-15f
#define MAX_ATANH (1.0f - 1e-5f)
#define ATT 16

#define LOG_NPB 11                 // nodes per bucket = 2048
#define NPB (1 << LOG_NPB)
#define MAXB 1024                  // max buckets (V <= 2^21)
#define NBLK 512                   // hist/scatter grid

// score table: s(vx, vy) on [-6.25, 6.25]^2, 512x512, bilinear
#define TDIM 512
#define TSPAN 12.5f
#define TSTEP (TSPAN / (float)(TDIM - 1))
#define TSCALE ((float)(TDIM - 1) / TSPAN)
#define TOFF (6.25f * TSCALE)

// ---- fast branch-free transcendentals --------------------------------------
__device__ __forceinline__ float fast_atanh(float z) {
    return 0.5f * __logf(__fdividef(1.0f + z, 1.0f - z));
}
__device__ __forceinline__ float fast_tanh(float z) {
    return 1.0f - __fdividef(2.0f, __expf(2.0f * z) + 1.0f);
}
__device__ __forceinline__ float gelu_exact(float u) {
    return 0.5f * u * (1.0f + erff(u * 0.70710678118654752f));
}

// ---------------- K0: build score table (exact erf; ~µs) -------------------
__global__ void __launch_bounds__(256) build_table_kernel(
        const float* __restrict__ W1, const float* __restrict__ b1,
        const float* __restrict__ W2, float2* __restrict__ tab) {
    const int idx = blockIdx.x * 256 + threadIdx.x;
    if (idx >= TDIM * TDIM) return;
    const int iy = idx >> 9;
    const int ix = idx & (TDIM - 1);
    const float vy  = fmaf((float)iy, TSTEP, -6.25f);
    const float vx0 = fmaf((float)ix, TSTEP, -6.25f);
    const float vx1 = fmaf((float)min(ix + 1, TDIM - 1), TSTEP, -6.25f);
    float s0 = 0.0f, s1 = 0.0f;
    #pragma unroll
    for (int k = 0; k < ATT; ++k) {
        const float w1x = W1[k], w1y = W1[ATT + k], bb = b1[k], w2 = W2[k];
        s0 = fmaf(gelu_exact(fmaf(vx0, w1x, fmaf(vy, w1y, bb))), w2, s0);
        s1 = fmaf(gelu_exact(fmaf(vx1, w1x, fmaf(vy, w1y, bb))), w2, s1);
    }
    tab[idx] = make_float2(s0, s1);
}

// ---------------- K1: per-block bucket histogram ---------------------------
__global__ void __launch_bounds__(256) hist_kernel(const int* __restrict__ row,
                                                   int E, int B,
                                                   unsigned* __restrict__ counts /*[B][NBLK]*/) {
    __shared__ unsigned h[MAXB];
    for (int i = threadIdx.x; i < B; i += 256) h[i] = 0u;
    __syncthreads();
    const int T = gridDim.x * 256;
    const int nv = E >> 2;
    const int4* row4 = (const int4*)row;
    for (int i = blockIdx.x * 256 + threadIdx.x; i < nv; i += T) {
        const int4 r = row4[i];
        atomicAdd(&h[((unsigned)r.x) >> LOG_NPB], 1u);
        atomicAdd(&h[((unsigned)r.y) >> LOG_NPB], 1u);
        atomicAdd(&h[((unsigned)r.z) >> LOG_NPB], 1u);
        atomicAdd(&h[((unsigned)r.w) >> LOG_NPB], 1u);
    }
    for (int e = (nv << 2) + blockIdx.x * 256 + threadIdx.x; e < E; e += T)
        atomicAdd(&h[((unsigned)row[e]) >> LOG_NPB], 1u);
    __syncthreads();
    for (int i = threadIdx.x; i < B; i += 256)
        counts[(size_t)i * gridDim.x + blockIdx.x] = h[i];
}

// ---------------- K2a: exclusive scan of each bucket's NBLK counts ---------
// NBLK = 512, 256 threads, exactly 2 elems/thread.
__global__ void __launch_bounds__(256) scan_blocks_kernel(const unsigned* __restrict__ counts,
                                                          unsigned* __restrict__ within,
                                                          unsigned* __restrict__ totals) {
    const int b = blockIdx.x;
    const unsigned* src = counts + (size_t)b * NBLK;
    unsigned* dst = within + (size_t)b * NBLK;
    __shared__ unsigned s[256];
    unsigned v0, v1;
    {
        const uint2 v = ((const uint2*)src)[threadIdx.x];
        v0 = v.x; v1 = v.y;
    }
    s[threadIdx.x] = v0 + v1;
    __syncthreads();
    for (int off = 1; off < 256; off <<= 1) {
        unsigned t = (threadIdx.x >= off) ? s[threadIdx.x - off] : 0u;
        __syncthreads();
        s[threadIdx.x] += t;
        __syncthreads();
    }
    unsigned base = (threadIdx.x > 0) ? s[threadIdx.x - 1] : 0u;
    uint2 o;
    o.x = base; o.y = base + v0;
    ((uint2*)dst)[threadIdx.x] = o;
    if (threadIdx.x == 255) totals[b] = s[255];
}

// ---------------- K2b: exclusive scan of bucket totals -> base[B+1] --------
__global__ void __launch_bounds__(256) scan_totals_kernel(const unsigned* __restrict__ totals,
                                                          unsigned* __restrict__ base, int B) {
    __shared__ unsigned s[256];
    unsigned vals[8];
    const int i0 = threadIdx.x * 8;
    unsigned sum = 0u;
    #pragma unroll
    for (int k = 0; k < 8; ++k) {
        vals[k] = (i0 + k < B) ? totals[i0 + k] : 0u;
        sum += vals[k];
    }
    s[threadIdx.x] = sum;
    __syncthreads();
    for (int off = 1; off < 256; off <<= 1) {
        unsigned t = (threadIdx.x >= off) ? s[threadIdx.x - off] : 0u;
        __syncthreads();
        s[threadIdx.x] += t;
        __syncthreads();
    }
    unsigned b0 = (threadIdx.x > 0) ? s[threadIdx.x - 1] : 0u;
    #pragma unroll
    for (int k = 0; k < 8; ++k) {
        if (i0 + k < B) base[i0 + k] = b0;
        b0 += vals[k];
    }
    if (threadIdx.x == 255) base[B] = s[255];
}

// ---------------- K3: scatter edges into bucket-sorted payload -------------
// payload word: (lrow:11 << 21) | col:21   (V <= 2^21)
__global__ void __launch_bounds__(256) scatter_kernel(const int* __restrict__ row,
                                                      const int* __restrict__ col,
                                                      int E, int B,
                                                      const unsigned* __restrict__ base,
                                                      const unsigned* __restrict__ within,
                                                      unsigned* __restrict__ payload) {
    __shared__ unsigned cur[MAXB];
    const int nblk = gridDim.x;
    for (int i = threadIdx.x; i < B; i += 256)
        cur[i] = base[i] + within[(size_t)i * nblk + blockIdx.x];
    __syncthreads();
    const int T = nblk * 256;
    const int nv = E >> 2;
    const int4* row4 = (const int4*)row;
    const int4* col4 = (const int4*)col;
    for (int i = blockIdx.x * 256 + threadIdx.x; i < nv; i += T) {
        const int4 r = row4[i];
        const int4 c = col4[i];
        {
            const unsigned rr = (unsigned)r.x;
            const unsigned pos = atomicAdd(&cur[rr >> LOG_NPB], 1u);
            payload[pos] = ((rr & (NPB - 1)) << 21) | (unsigned)c.x;
        }
        {
            const unsigned rr = (unsigned)r.y;
            const unsigned pos = atomicAdd(&cur[rr >> LOG_NPB], 1u);
            payload[pos] = ((rr & (NPB - 1)) << 21) | (unsigned)c.y;
        }
        {
            const unsigned rr = (unsigned)r.z;
            const unsigned pos = atomicAdd(&cur[rr >> LOG_NPB], 1u);
            payload[pos] = ((rr & (NPB - 1)) << 21) | (unsigned)c.z;
        }
        {
            const unsigned rr = (unsigned)r.w;
            const unsigned pos = atomicAdd(&cur[rr >> LOG_NPB], 1u);
            payload[pos] = ((rr & (NPB - 1)) << 21) | (unsigned)c.w;
        }
    }
    for (int e = (nv << 2) + blockIdx.x * 256 + threadIdx.x; e < E; e += T) {
        const unsigned rr = (unsigned)row[e];
        const unsigned pos = atomicAdd(&cur[rr >> LOG_NPB], 1u);
        payload[pos] = ((rr & (NPB - 1)) << 21) | (unsigned)col[e];
    }
}

// ---------------- K4: per-bucket LDS accumulate + node epilogue ------------
__device__ __forceinline__ void edge_single(unsigned p,
        const float2* __restrict__ x, const float2* __restrict__ tab,
        const float2* sxi, float* sden, float* smx, float* smy) {
    const unsigned lrow = p >> 21;
    const unsigned c = p & 0x1FFFFFu;
    const float2 xj = x[c];                      // random gather — the floor
    const float2 xi = sxi[lrow];                 // LDS

    const float ax = -xi.x, ay = -xi.y;
    const float bx = xj.x,  by = xj.y;
    const float a2 = ax * ax + ay * ay;
    const float b2 = bx * bx + by * by;
    const float ab = ax * bx + ay * by;
    const float ca = 1.0f + 2.0f * ab + b2;
    const float cb = 1.0f - a2;
    const float dn = fmaxf(1.0f + 2.0f * ab + a2 * b2, EPSF);
    const float rdn = __fdividef(1.0f, dn);
    const float subx = (ca * ax + cb * bx) * rdn;
    const float suby = (ca * ay + cb * by) * rdn;

    const float n = fmaxf(sqrtf(subx * subx + suby * suby), EPSF);
    const float M = fmaxf(1.0f - (xi.x * xi.x + xi.y * xi.y), EPSF);
    const float scl = M * fast_atanh(fminf(n, MAX_ATANH)) * __fdividef(1.0f, n);
    const float vx = scl * subx;
    const float vy = scl * suby;

    float tx = fmaf(vx, TSCALE, TOFF);
    float ty = fmaf(vy, TSCALE, TOFF);
    tx = fminf(fmaxf(tx, 0.0f), 510.999f);
    ty = fminf(fmaxf(ty, 0.0f), 510.999f);
    const int ix = (int)tx;
    const int iy = (int)ty;
    const float fx = tx - (float)ix;
    const float fy = ty - (float)iy;
    const int baseIdx = (iy << 9) + ix;
    const float2 r0 = tab[baseIdx];
    const float2 r1 = tab[baseIdx + TDIM];
    const float s0 = fmaf(fx, r0.y - r0.x, r0.x);
    const float s1 = fmaf(fx, r1.y - r1.x, r1.x);
    const float s  = fmaf(fy, s1 - s0, s0);

    const float ee = __expf(s);
    atomicAdd(&sden[lrow], ee);
    atomicAdd(&smx[lrow], ee * vx);
    atomicAdd(&smy[lrow], ee * vy);
}

__global__ void __launch_bounds__(512, 8) bucket_reduce_kernel(
        const float2* __restrict__ x,
        const float2* __restrict__ tab,
        const unsigned* __restrict__ base,
        const unsigned* __restrict__ payload,
        const int* __restrict__ depth,
        const float* __restrict__ depth_scale,
        const float* __restrict__ depth_theta,
        const float* __restrict__ eta_p,
        float2* __restrict__ out, int V) {
    __shared__ float  sden[NPB];
    __shared__ float  smx[NPB];
    __shared__ float  smy[NPB];
    __shared__ float2 sxi[NPB];
    const int b = blockIdx.x;
    const int nodeBase = b << LOG_NPB;
    for (int i = threadIdx.x; i < NPB; i += 512) {
        sden[i] = 0.f; smx[i] = 0.f; smy[i] = 0.f;
        sxi[i] = x[nodeBase + i];
    }
    __syncthreads();

    const unsigned e0 = base[b], e1 = base[b + 1];
    for (unsigned e = e0 + threadIdx.x; e < e1; e += 512)
        edge_single(payload[e], x, tab, sxi, sden, smx, smy);
    __syncthreads();

    // node epilogue: normalize, depth mixer, exp-map
    const float eta = eta_p[0];
    for (int i = threadIdx.x; i < NPB; i += 512) {
        const int v = nodeBase + i;
        if (v >= V) break;
        const float rdv = __fdividef(1.0f, fmaxf(sden[i], EPSF));
        const float mx = smx[i] * rdv;
        const float my = smy[i] * rdv;

        const int d = min(depth[v], 511);
        const float k   = depth_scale[d];
        const float ang = depth_theta[d];
        const float cs = __cosf(ang), sn = __sinf(ang);
        const float m0 = eta * (k * (cs * mx - sn * my));
        const float m1 = eta * (k * (sn * mx + cs * my));

        const float2 xi = sxi[i];

        const float n = fmaxf(sqrtf(m0 * m0 + m1 * m1), EPSF);
        const float M = fmaxf(1.0f - (xi.x * xi.x + xi.y * xi.y), EPSF);
        const float t = fast_tanh(__fdividef(n, M));
        const float tn = t * __fdividef(1.0f, n);
        const float bx = tn * m0;
        const float by = tn * m1;

        const float a2 = xi.x * xi.x + xi.y * xi.y;
        const float b2 = bx * bx + by * by;
        const float ab = xi.x * bx + xi.y * by;
        const float ca = 1.0f + 2.0f * ab + b2;
        const float cb = 1.0f - a2;
        const float dn = fmaxf(1.0f + 2.0f * ab + a2 * b2, EPSF);
        const float rdn = __fdividef(1.0f, dn);

        out[v] = make_float2((ca * xi.x + cb * bx) * rdn,
                             (ca * xi.y + cb * by) * rdn);
    }
}

extern "C" void kernel_launch(void* const* d_in, const int* in_sizes, int n_in,
                              void* d_out, int out_size, void* d_ws, size_t ws_size,
                              hipStream_t stream) {
    const float2* x          = (const float2*)d_in[0];
    const float*  W1         = (const float*)d_in[1];
    const float*  b1         = (const float*)d_in[2];
    const float*  W2         = (const float*)d_in[3];
    const float*  eta        = (const float*)d_in[4];
    const float*  dscale     = (const float*)d_in[5];
    const float*  dtheta     = (const float*)d_in[6];
    const int*    edge_index = (const int*)d_in[7];
    const int*    depth      = (const int*)d_in[8];

    const int V = in_sizes[0] / 2;
    const int E = in_sizes[7] / 2;
    const int B = (V + NPB - 1) >> LOG_NPB;       // 1024 buckets

    const int* row = edge_index;
    const int* col = edge_index + E;

    // workspace layout (all u32): payload[E] | counts[B*NBLK] | within[B*NBLK]
    //                             | totals[B] | base[B+1]
    // score table (2MB float2) reuses `within` (dead after scatter).
    unsigned* payload = (unsigned*)d_ws;
    unsigned* counts  = payload + E;
    unsigned* within  = counts + (size_t)B * NBLK;
    unsigned* totals  = within + (size_t)B * NBLK;
    unsigned* base    = totals + B;
    float2*   tab     = (float2*)within;

    hist_kernel<<<NBLK, 256, 0, stream>>>(row, E, B, counts);
    scan_blocks_kernel<<<B, 256, 0, stream>>>(counts, within, totals);
    scan_totals_kernel<<<1, 256, 0, stream>>>(totals, base, B);
    scatter_kernel<<<NBLK, 256, 0, stream>>>(row, col, E, B, base, within, payload);
    build_table_kernel<<<(TDIM * TDIM) / 256, 256, 0, stream>>>(W1, b1, W2, tab);
    bucket_reduce_kernel<<<B, 512, 0, stream>>>(x, tab, base, payload,
                                                depth, dscale, dtheta, eta,
                                                (float2*)d_out, V);
}